// Round 6
// baseline (141.514 us; speedup 1.0000x reference)
//
#include <hip/hip_runtime.h>
#include <cmath>

#define BB   8
#define NPIX 256
#define MM   8192
#define NCP  24576
#define NCA  24576
#define EPSF 1e-16f

#define KC   64    // K-chunk (y's per chunk) = two MFMA K-steps
#define TMB  128   // m's per block
#define NT   512   // threads per block (8 waves, 2 waves/SIMD)

// ---- d_out layout (floats)
#define VIS_OFF    0
#define VISAMP_OFF (BB * 2 * MM)            // 131072
#define CPH_OFF    (VISAMP_OFF + BB * MM)   // 196608
#define LCA_OFF    (CPH_OFF + BB * NCP)     // 393216

typedef __bf16 bf16x8 __attribute__((ext_vector_type(8)));
typedef float  f32x4  __attribute__((ext_vector_type(4)));

// Window layout for B (KC=64): element (row,k) -> (row>>4)*1024 + (k>>3)*128
// + (row&15)*8 + (k&7). 16 B lane stride within each 16-lane phase -> 2-way
// bank aliasing only (free, m136).
// SESSION RULES (hard-won):
//  - no cross-kernel dataflow through d_ws (R5/R6); d_out is proven.
//  - NUMERICS: full 3-term split mandatory (R12: 2-term -> cphase 361 deg).
//  - R18: dbuf+1-barrier regressed. R2: co-resident blocks regressed.
//    R3: in-register A = neutral. R4: 1 wave/SIMD = 86 us (need the 2nd
//    wave for latency hiding). R5: cross-barrier reg pipelining SPILLED
//    (WRITE_SIZE 768KB->14.9MB) and was net neutral => ZERO reg headroom
//    at 2 waves/SIMD; nothing may live across the MFMA phase.
//  - THIS ROUND: KC 32->64. Halves the stall windows (8 chunks->4) and
//    barriers (16->8) with NO added live registers: second K-step's A
//    frags are generated BETWEEN the two MFMA half-phases (one frag set
//    live at a time, R3 discipline). Bit-identical arithmetic to R3
//    (same genA sequence, same per-acc K-step order, same epilogue).
//  - WRITE_SIZE is the spill tripwire (768 KB = clean).
//  - residual ~57 us outside the vis kernel is harness-fixed; vis is the
//    only lever.
#define WIDX64(row, k8) (((row) >> 4) * 1024 + (k8) * 128 + ((row) & 15) * 8)

// range reduction: theta == k*n (mod 2pi) in [-pi,pi] (keeps sincosf fast).
__device__ __forceinline__ float red2pi(float k, float n)
{
    const double t = (double)k * (double)n * 0.15915494309189535;  // /(2pi)
    const double f = t - rint(t);
    return (float)(f * 6.283185307179586);
}

// Block: 128 m's x 256 x's x 1 batch, 8 waves. Ev via per-lane rotor
// recurrences directly in MFMA A-fragment layout (row=w*16+ln15, oct=q).
// 3-term split MFMA (hh, hl, lh) per plane. KC=64: 2 K-steps per chunk.
__global__ __launch_bounds__(NT, 2)
void nufft_vis_mfma(const float* __restrict__ images,
                    const float* __restrict__ ktraj,
                    const float* __restrict__ pulsefac,
                    float* __restrict__ out)
{
    __shared__ __align__(16) __bf16 sBh[NPIX * KC];   // 32 KB img hi
    __shared__ __align__(16) __bf16 sBl[NPIX * KC];   // 32 KB img lo

    const int tid  = threadIdx.x;
    const int m0   = blockIdx.x * TMB;
    const int b    = blockIdx.y;
    const int lane = tid & 63;
    const int w    = tid >> 6;        // wave 0..7
    const int ln15 = lane & 15;
    const int q    = lane >> 4;       // k-octet 0..3

    // ---- A rotor state: lane owns Ev row (m0 + w*16 + ln15), k-octet q.
    const float kvm = ktraj[m0 + w * 16 + ln15];
    float r1s, r1c, r32s, r32c, as_, ac_;
    sincosf(kvm, &r1s, &r1c);                          // rot1: |kvm| <= pi
    sincosf(red2pi(kvm, 32.0f), &r32s, &r32c);         // rot32
    sincosf(red2pi(kvm, (float)(q * 8 - 128)), &as_, &ac_);  // anchor @ y0=0
    float anr = ac_, ani = -as_;

    // B staging: x = tid&255, octet group = (tid>>8)*4 .. +3
    const int bx    = tid & 255;
    const int bhalf = tid >> 8;       // 0..1
    const float* imgb = images + b * NPIX * NPIX + bx;

    // gen A fragments for the next 8 y's (anchor pos), advance anchor by 32
    auto genA = [&](bf16x8& Rh, bf16x8& Rl, bf16x8& Ih, bf16x8& Il) {
        float er = anr, ei = ani;   // Ev = exp(-i*kv*(y-128))
        #pragma unroll
        for (int j = 0; j < 8; ++j) {
            __bf16 h = (__bf16)er;
            Rh[j] = h; Rl[j] = (__bf16)(er - (float)h);
            h = (__bf16)ei;
            Ih[j] = h; Il[j] = (__bf16)(ei - (float)h);
            const float nr = er * r1c + ei * r1s;   // *= e^{-i*kvm}
            const float ni = ei * r1c - er * r1s;
            er = nr; ei = ni;
        }
        const float nr = anr * r32c + ani * r32s;   // anchor *= e^{-i*kv*32}
        const float ni = ani * r32c - anr * r32s;
        anr = nr; ani = ni;
    };

    f32x4 acc[2][16];                 // [0]=real plane, [1]=imag plane
    #pragma unroll
    for (int rt = 0; rt < 2; ++rt)
        #pragma unroll
        for (int ct = 0; ct < 16; ++ct)
            acc[rt][ct] = (f32x4){0.f, 0.f, 0.f, 0.f};

    for (int c = 0; c < NPIX / KC; ++c) {
        const int y0 = c * KC;

        // ---- A fragments for K-step 0 of this chunk (y0 + q*8)
        bf16x8 fRh, fRl, fIh, fIl;
        genA(fRh, fRl, fIh, fIl);

        // ---- stage B: img[b, 4 octets, x=bx] -> hi/lo, window layout
        #pragma unroll
        for (int oo = 0; oo < 4; ++oo) {
            const int oct = bhalf * 4 + oo;
            bf16x8 bh, bl;
            #pragma unroll
            for (int j = 0; j < 8; ++j) {
                const float v = imgb[(y0 + oct * 8 + j) * NPIX];
                const __bf16 h = (__bf16)v;
                bh[j] = h; bl[j] = (__bf16)(v - (float)h);
            }
            const int bo = WIDX64(bx, oct);
            *(bf16x8*)&sBh[bo] = bh;
            *(bf16x8*)&sBl[bo] = bl;
        }
        __syncthreads();

        // ---- MFMA half-phase 0: K-step 0 (k8 = q)
        #pragma unroll
        for (int ct = 0; ct < 16; ++ct) {
            const int bro = WIDX64(ct * 16 + ln15, q);
            const bf16x8 bh = *(const bf16x8*)&sBh[bro];
            const bf16x8 bl = *(const bf16x8*)&sBl[bro];
            acc[0][ct] = __builtin_amdgcn_mfma_f32_16x16x32_bf16(fRh, bh, acc[0][ct], 0, 0, 0);
            acc[0][ct] = __builtin_amdgcn_mfma_f32_16x16x32_bf16(fRh, bl, acc[0][ct], 0, 0, 0);
            acc[0][ct] = __builtin_amdgcn_mfma_f32_16x16x32_bf16(fRl, bh, acc[0][ct], 0, 0, 0);
            acc[1][ct] = __builtin_amdgcn_mfma_f32_16x16x32_bf16(fIh, bh, acc[1][ct], 0, 0, 0);
            acc[1][ct] = __builtin_amdgcn_mfma_f32_16x16x32_bf16(fIh, bl, acc[1][ct], 0, 0, 0);
            acc[1][ct] = __builtin_amdgcn_mfma_f32_16x16x32_bf16(fIl, bh, acc[1][ct], 0, 0, 0);
        }

        // ---- A fragments for K-step 1 (y0 + 32 + q*8); frag set reused
        genA(fRh, fRl, fIh, fIl);

        // ---- MFMA half-phase 1: K-step 1 (k8 = 4 + q)
        #pragma unroll
        for (int ct = 0; ct < 16; ++ct) {
            const int bro = WIDX64(ct * 16 + ln15, 4 + q);
            const bf16x8 bh = *(const bf16x8*)&sBh[bro];
            const bf16x8 bl = *(const bf16x8*)&sBl[bro];
            acc[0][ct] = __builtin_amdgcn_mfma_f32_16x16x32_bf16(fRh, bh, acc[0][ct], 0, 0, 0);
            acc[0][ct] = __builtin_amdgcn_mfma_f32_16x16x32_bf16(fRh, bl, acc[0][ct], 0, 0, 0);
            acc[0][ct] = __builtin_amdgcn_mfma_f32_16x16x32_bf16(fRl, bh, acc[0][ct], 0, 0, 0);
            acc[1][ct] = __builtin_amdgcn_mfma_f32_16x16x32_bf16(fIh, bh, acc[1][ct], 0, 0, 0);
            acc[1][ct] = __builtin_amdgcn_mfma_f32_16x16x32_bf16(fIh, bl, acc[1][ct], 0, 0, 0);
            acc[1][ct] = __builtin_amdgcn_mfma_f32_16x16x32_bf16(fIl, bh, acc[1][ct], 0, 0, 0);
        }
        __syncthreads();
    }

    // ---- fused stage 2 (in-wave): kdata[b,m] = sum_x tmp[m,x] * Eu[m,x]
    // C layout: col(x within tile) = ln15, row(m within tile) = 4*q + r
    #pragma unroll
    for (int r = 0; r < 4; ++r) {
        const int m = m0 + w * 16 + q * 4 + r;
        const float ku = ktraj[MM + m];
        float s0, c0, s16, c16;
        sincosf(red2pi(ku, (float)(ln15 - 128)), &s0, &c0);
        sincosf(red2pi(ku, 16.0f), &s16, &c16);
        float er = c0, ei = -s0;       // Eu at x = ln15 - 128, step +16 per ct
        float sr = 0.f, si = 0.f;
        #pragma unroll
        for (int ct = 0; ct < 16; ++ct) {
            const float tr = acc[0][ct][r];
            const float ti = acc[1][ct][r];
            sr = fmaf(tr, er, fmaf(-ti, ei, sr));
            si = fmaf(tr, ei, fmaf(ti, er, si));
            const float nr = er * c16 + ei * s16;   // *= e^{-i*ku*16}
            const float ni = ei * c16 - er * s16;
            er = nr; ei = ni;
        }
        // reduce over the 16 lanes of this quad (masks <16 stay in-quad)
        #pragma unroll
        for (int off = 8; off >= 1; off >>= 1) {
            sr += __shfl_xor(sr, off);
            si += __shfl_xor(si, off);
        }
        if (ln15 == 0) {
            const float pr = pulsefac[m];
            const float pi = pulsefac[MM + m];
            const float vr = sr * pr - si * pi;
            const float vi = sr * pi + si * pr;
            out[b * 2 * MM + m]      = vr;
            out[b * 2 * MM + MM + m] = vi;
            out[VISAMP_OFF + b * MM + m] = sqrtf(vr * vr + vi * vi + EPSF);
        }
    }
}

// polynomial atan2 (A&S 4.4.49, err <= ~1e-5 rad), fully predicated
__device__ __forceinline__ float fast_atan2f(float y, float x)
{
    const float ax = fabsf(x), ay = fabsf(y);
    const float mx = fmaxf(ax, ay), mn = fminf(ax, ay);
    const float a  = mn / fmaxf(mx, 1e-37f);
    const float s  = a * a;
    float r = 0.0208351f;
    r = fmaf(r, s, -0.0851330f);
    r = fmaf(r, s,  0.1801410f);
    r = fmaf(r, s, -0.3302995f);
    r = fmaf(r, s,  0.9998660f);
    r *= a;
    r = (ay > ax) ? (1.57079632679f - r) : r;
    r = (x < 0.0f) ? (3.14159265359f - r) : r;
    return (y < 0.0f) ? -r : r;
}

// fused cphase + logcamp. Each block serves ONE batch (NCP % 256 == 0):
// stage that batch's vis (64 KB) into LDS, scatters hit LDS.
__global__ __launch_bounds__(256)
void gather_fused(const float* __restrict__ vis,
                  const float* __restrict__ sign,
                  const int* __restrict__ cind,
                  const int* __restrict__ caind,
                  float* __restrict__ out)
{
    __shared__ float sv[2 * MM];      // 64 KB: [0,MM)=re, [MM,2MM)=im

    const int i = blockIdx.x * 256 + threadIdx.x;
    const int b = i / NCP;
    const int n = i - b * NCP;

    {
        const float4* g4 = (const float4*)(vis + b * 2 * MM);
        float4* s4 = (float4*)sv;
        #pragma unroll
        for (int j = 0; j < (2 * MM / 4) / 256; ++j)
            s4[j * 256 + threadIdx.x] = g4[j * 256 + threadIdx.x];
    }
    __syncthreads();

    float cp = 0.f;
    #pragma unroll
    for (int k = 0; k < 3; ++k) {
        const int m = cind[k * NCP + n];
        cp += sign[k * NCP + n] * fast_atan2f(sv[MM + m], sv[m]);
    }
    out[CPH_OFF + i] = cp * 57.29577951308232f;   // 180/pi

    // logcamp = 0.5*log((p1*p2)/(p3*p4)), p = vr^2+vi^2+eps — one log call
    float p[4];
    #pragma unroll
    for (int k = 0; k < 4; ++k) {
        const int m = caind[k * NCA + n];
        const float vr = sv[m];
        const float vi = sv[MM + m];
        p[k] = vr * vr + vi * vi + EPSF;
    }
    out[LCA_OFF + i] = 0.5f * __logf((p[0] * p[1]) / (p[2] * p[3]));
}

extern "C" void kernel_launch(void* const* d_in, const int* in_sizes, int n_in,
                              void* d_out, int out_size, void* d_ws, size_t ws_size,
                              hipStream_t stream)
{
    const float* images   = (const float*)d_in[0];
    const float* ktraj    = (const float*)d_in[1];
    const float* pulsefac = (const float*)d_in[2];
    const float* csign    = (const float*)d_in[3];
    const int*   cind     = (const int*)d_in[4];
    const int*   caind    = (const int*)d_in[5];
    float* out = (float*)d_out;

    dim3 grid(MM / TMB, BB);
    nufft_vis_mfma<<<grid, NT, 0, stream>>>(images, ktraj, pulsefac, out);
    gather_fused<<<BB * NCP / 256, 256, 0, stream>>>(out, csign, cind, caind, out);
}

// Round 7
// 123.293 us; speedup vs baseline: 1.1478x; 1.1478x over previous
//
#include <hip/hip_runtime.h>
#include <cmath>

#define BB   8
#define NPIX 256
#define MM   8192
#define NCP  24576
#define NCA  24576
#define EPSF 1e-16f

#define KC   32    // K-chunk (x's per chunk) = one MFMA K-step
#define TMB  128   // m's per block
#define NT   512   // threads per block (8 waves, 2 waves/SIMD)

// ---- d_out layout (floats)
#define VIS_OFF    0
#define VISAMP_OFF (BB * 2 * MM)            // 131072
#define CPH_OFF    (VISAMP_OFF + BB * MM)   // 196608
#define LCA_OFF    (CPH_OFF + BB * NCP)     // 393216

typedef __bf16 bf16x8 __attribute__((ext_vector_type(8)));
typedef float  f32x4  __attribute__((ext_vector_type(4)));

// Window layout for B: element (row,k) -> (row>>4)*512 + (k>>3)*128 +
// (row&15)*8 + (k&7). 16 B lane stride within each 16-lane phase -> 2-way
// bank aliasing only (free, m136).
// SESSION RULES (hard-won):
//  - no cross-kernel dataflow through d_ws (R5/R6); d_out is proven.
//  - NUMERICS: full 3-term split mandatory (R12: 2-term -> cphase 361 deg).
//  - CLOSED LEVERS: R18 dbuf; R2 co-resident blocks; R4 1-wave/SIMD ILP
//    (86 us serial path; 2nd wave hides ~28 us); R5 cross-barrier reg
//    pipelining (spills: ZERO reg headroom at 2 waves/SIMD); R6 KC=64
//    (regressed 58->87 us, mechanism NOT understood -> chunk-size changes
//    closed). R3 in-register A: neutral, kept (smaller LDS).
//  - THIS ROUND: contraction-order swap (x-first). k-dim = x, so the B
//    fragment is 8 CONTIGUOUS floats of an img row: staging = 4x
//    global_load_dwordx4 per thread per chunk (was 16 strided dwords +
//    16 addr calcs). kv/ku swap roles (A-rotor uses ktraj[1]=ku, epilogue
//    uses ktraj[0]=kv). Everything else structurally identical to R3.
//    NOT bit-identical (sum order swaps) but error scheme is symmetric.
//  - WRITE_SIZE is the spill tripwire (768 KB = clean).
//  - residual ~57 us outside the vis kernel is harness-fixed; vis is the
//    only lever.
#define WIDX(row, k8) (((row) >> 4) * 512 + (k8) * 128 + ((row) & 15) * 8)

// range reduction: theta == k*n (mod 2pi) in [-pi,pi] (keeps sincosf fast).
__device__ __forceinline__ float red2pi(float k, float n)
{
    const double t = (double)k * (double)n * 0.15915494309189535;  // /(2pi)
    const double f = t - rint(t);
    return (float)(f * 6.283185307179586);
}

// Block: 128 m's x 256 y's x 1 batch, 8 waves. Stage 1 contracts over x:
// tmp2[m,y] = sum_x img[b,y,x] * Eu[m,x]  (A = Eu rotor, in-register;
// B = img rows, k = x contiguous). Stage 2: kdata = sum_y tmp2 * Ev[m,y].
// 3-term split MFMA (hh, hl, lh) per plane.
__global__ __launch_bounds__(NT, 2)
void nufft_vis_mfma(const float* __restrict__ images,
                    const float* __restrict__ ktraj,
                    const float* __restrict__ pulsefac,
                    float* __restrict__ out)
{
    __shared__ __align__(16) __bf16 sBh[NPIX * KC];   // 16 KB img hi
    __shared__ __align__(16) __bf16 sBl[NPIX * KC];   // 16 KB img lo

    const int tid  = threadIdx.x;
    const int m0   = blockIdx.x * TMB;
    const int b    = blockIdx.y;
    const int lane = tid & 63;
    const int w    = tid >> 6;        // wave 0..7
    const int ln15 = lane & 15;
    const int q    = lane >> 4;       // k-octet 0..3

    // ---- A rotor state: lane owns Eu row (m0 + w*16 + ln15), k-octet q.
    // Eu = exp(-i*ku*(x-128)); ku = ktraj[1][m].
    const float kum = ktraj[MM + m0 + w * 16 + ln15];
    float r1s, r1c, r32s, r32c, as_, ac_;
    sincosf(kum, &r1s, &r1c);                          // rot1: |kum| <= pi
    sincosf(red2pi(kum, 32.0f), &r32s, &r32c);         // rot32
    sincosf(red2pi(kum, (float)(q * 8 - 128)), &as_, &ac_);  // anchor @ x0=0
    float anr = ac_, ani = -as_;

    // B staging: y-row = tid&255, octet pair = (tid>>8)*2 .. +1.
    // Thread's data: img[b][y][c*32 + bhalf*16 .. +16) = 64 B contiguous.
    const int by    = tid & 255;
    const int bhalf = tid >> 8;       // 0..1
    const float* imgb = images + b * NPIX * NPIX + by * NPIX;

    f32x4 acc[2][16];                 // [0]=real plane, [1]=imag plane
    #pragma unroll
    for (int rt = 0; rt < 2; ++rt)
        #pragma unroll
        for (int ct = 0; ct < 16; ++ct)
            acc[rt][ct] = (f32x4){0.f, 0.f, 0.f, 0.f};

    for (int x0 = 0; x0 < NPIX; x0 += KC) {
        // ---- A fragments in-register: Eu[row, x0 + q*8 .. +8), hi/lo
        bf16x8 fRh, fRl, fIh, fIl;
        {
            float er = anr, ei = ani;   // Eu = exp(-i*ku*(x-128))
            #pragma unroll
            for (int j = 0; j < 8; ++j) {
                __bf16 h = (__bf16)er;
                fRh[j] = h; fRl[j] = (__bf16)(er - (float)h);
                h = (__bf16)ei;
                fIh[j] = h; fIl[j] = (__bf16)(ei - (float)h);
                const float nr = er * r1c + ei * r1s;   // *= e^{-i*kum}
                const float ni = ei * r1c - er * r1s;
                er = nr; ei = ni;
            }
            // advance anchor to next chunk: *= e^{-i*kum*32}
            const float nr = anr * r32c + ani * r32s;
            const float ni = ani * r32c - anr * r32s;
            anr = nr; ani = ni;
        }
        // ---- stage B: img[b, y=by, x-octets] -> hi/lo, window layout.
        // Contiguous 8-float row segments: 2x float4 per octet.
        #pragma unroll
        for (int oo = 0; oo < 2; ++oo) {
            const int oct = bhalf * 2 + oo;
            const float4 v0 = *(const float4*)&imgb[x0 + oct * 8];
            const float4 v1 = *(const float4*)&imgb[x0 + oct * 8 + 4];
            float vv[8] = {v0.x, v0.y, v0.z, v0.w, v1.x, v1.y, v1.z, v1.w};
            bf16x8 bh, bl;
            #pragma unroll
            for (int j = 0; j < 8; ++j) {
                const float v = vv[j];
                const __bf16 h = (__bf16)v;
                bh[j] = h; bl[j] = (__bf16)(v - (float)h);
            }
            const int bo = WIDX(by, oct);
            *(bf16x8*)&sBh[bo] = bh;
            *(bf16x8*)&sBl[bo] = bl;
        }
        __syncthreads();

        // ---- MFMA: wave w owns A-rows [16w, 16w+16); ct tiles = y
        #pragma unroll
        for (int ct = 0; ct < 16; ++ct) {
            const int bro = WIDX(ct * 16 + ln15, q);
            const bf16x8 bh = *(const bf16x8*)&sBh[bro];
            const bf16x8 bl = *(const bf16x8*)&sBl[bro];
            acc[0][ct] = __builtin_amdgcn_mfma_f32_16x16x32_bf16(fRh, bh, acc[0][ct], 0, 0, 0);
            acc[0][ct] = __builtin_amdgcn_mfma_f32_16x16x32_bf16(fRh, bl, acc[0][ct], 0, 0, 0);
            acc[0][ct] = __builtin_amdgcn_mfma_f32_16x16x32_bf16(fRl, bh, acc[0][ct], 0, 0, 0);
            acc[1][ct] = __builtin_amdgcn_mfma_f32_16x16x32_bf16(fIh, bh, acc[1][ct], 0, 0, 0);
            acc[1][ct] = __builtin_amdgcn_mfma_f32_16x16x32_bf16(fIh, bl, acc[1][ct], 0, 0, 0);
            acc[1][ct] = __builtin_amdgcn_mfma_f32_16x16x32_bf16(fIl, bh, acc[1][ct], 0, 0, 0);
        }
        __syncthreads();
    }

    // ---- fused stage 2 (in-wave): kdata[b,m] = sum_y tmp2[m,y] * Ev[m,y]
    // C layout: col(y within tile) = ln15, row(m within tile) = 4*q + r
    #pragma unroll
    for (int r = 0; r < 4; ++r) {
        const int m = m0 + w * 16 + q * 4 + r;
        const float kv = ktraj[m];     // ktraj[0][m] drives the y rotor
        float s0, c0, s16, c16;
        sincosf(red2pi(kv, (float)(ln15 - 128)), &s0, &c0);
        sincosf(red2pi(kv, 16.0f), &s16, &c16);
        float er = c0, ei = -s0;       // Ev at y = ln15 - 128, step +16 per ct
        float sr = 0.f, si = 0.f;
        #pragma unroll
        for (int ct = 0; ct < 16; ++ct) {
            const float tr = acc[0][ct][r];
            const float ti = acc[1][ct][r];
            sr = fmaf(tr, er, fmaf(-ti, ei, sr));
            si = fmaf(tr, ei, fmaf(ti, er, si));
            const float nr = er * c16 + ei * s16;   // *= e^{-i*kv*16}
            const float ni = ei * c16 - er * s16;
            er = nr; ei = ni;
        }
        // reduce over the 16 lanes of this quad (masks <16 stay in-quad)
        #pragma unroll
        for (int off = 8; off >= 1; off >>= 1) {
            sr += __shfl_xor(sr, off);
            si += __shfl_xor(si, off);
        }
        if (ln15 == 0) {
            const float pr = pulsefac[m];
            const float pi = pulsefac[MM + m];
            const float vr = sr * pr - si * pi;
            const float vi = sr * pi + si * pr;
            out[b * 2 * MM + m]      = vr;
            out[b * 2 * MM + MM + m] = vi;
            out[VISAMP_OFF + b * MM + m] = sqrtf(vr * vr + vi * vi + EPSF);
        }
    }
}

// polynomial atan2 (A&S 4.4.49, err <= ~1e-5 rad), fully predicated
__device__ __forceinline__ float fast_atan2f(float y, float x)
{
    const float ax = fabsf(x), ay = fabsf(y);
    const float mx = fmaxf(ax, ay), mn = fminf(ax, ay);
    const float a  = mn / fmaxf(mx, 1e-37f);
    const float s  = a * a;
    float r = 0.0208351f;
    r = fmaf(r, s, -0.0851330f);
    r = fmaf(r, s,  0.1801410f);
    r = fmaf(r, s, -0.3302995f);
    r = fmaf(r, s,  0.9998660f);
    r *= a;
    r = (ay > ax) ? (1.57079632679f - r) : r;
    r = (x < 0.0f) ? (3.14159265359f - r) : r;
    return (y < 0.0f) ? -r : r;
}

// fused cphase + logcamp. Each block serves ONE batch (NCP % 256 == 0):
// stage that batch's vis (64 KB) into LDS, scatters hit LDS.
__global__ __launch_bounds__(256)
void gather_fused(const float* __restrict__ vis,
                  const float* __restrict__ sign,
                  const int* __restrict__ cind,
                  const int* __restrict__ caind,
                  float* __restrict__ out)
{
    __shared__ float sv[2 * MM];      // 64 KB: [0,MM)=re, [MM,2MM)=im

    const int i = blockIdx.x * 256 + threadIdx.x;
    const int b = i / NCP;
    const int n = i - b * NCP;

    {
        const float4* g4 = (const float4*)(vis + b * 2 * MM);
        float4* s4 = (float4*)sv;
        #pragma unroll
        for (int j = 0; j < (2 * MM / 4) / 256; ++j)
            s4[j * 256 + threadIdx.x] = g4[j * 256 + threadIdx.x];
    }
    __syncthreads();

    float cp = 0.f;
    #pragma unroll
    for (int k = 0; k < 3; ++k) {
        const int m = cind[k * NCP + n];
        cp += sign[k * NCP + n] * fast_atan2f(sv[MM + m], sv[m]);
    }
    out[CPH_OFF + i] = cp * 57.29577951308232f;   // 180/pi

    // logcamp = 0.5*log((p1*p2)/(p3*p4)), p = vr^2+vi^2+eps — one log call
    float p[4];
    #pragma unroll
    for (int k = 0; k < 4; ++k) {
        const int m = caind[k * NCA + n];
        const float vr = sv[m];
        const float vi = sv[MM + m];
        p[k] = vr * vr + vi * vi + EPSF;
    }
    out[LCA_OFF + i] = 0.5f * __logf((p[0] * p[1]) / (p[2] * p[3]));
}

extern "C" void kernel_launch(void* const* d_in, const int* in_sizes, int n_in,
                              void* d_out, int out_size, void* d_ws, size_t ws_size,
                              hipStream_t stream)
{
    const float* images   = (const float*)d_in[0];
    const float* ktraj    = (const float*)d_in[1];
    const float* pulsefac = (const float*)d_in[2];
    const float* csign    = (const float*)d_in[3];
    const int*   cind     = (const int*)d_in[4];
    const int*   caind    = (const int*)d_in[5];
    float* out = (float*)d_out;

    dim3 grid(MM / TMB, BB);
    nufft_vis_mfma<<<grid, NT, 0, stream>>>(images, ktraj, pulsefac, out);
    gather_fused<<<BB * NCP / 256, 256, 0, stream>>>(out, csign, cind, caind, out);
}

// Round 8
// 120.699 us; speedup vs baseline: 1.1725x; 1.0215x over previous
//
#include <hip/hip_runtime.h>
#include <cmath>

#define BB   8
#define NPIX 256
#define MM   8192
#define NCP  24576
#define NCA  24576
#define EPSF 1e-16f

#define KC   32    // y's per chunk = two 32x32x16 K-steps
#define TMB  128   // m's per block
#define NT   512   // threads per block (8 waves, 2 waves/SIMD)

// ---- d_out layout (floats)
#define VIS_OFF    0
#define VISAMP_OFF (BB * 2 * MM)            // 131072
#define CPH_OFF    (VISAMP_OFF + BB * MM)   // 196608
#define LCA_OFF    (CPH_OFF + BB * NCP)     // 393216

typedef __bf16 bf16x8 __attribute__((ext_vector_type(8)));
typedef float  f32x4  __attribute__((ext_vector_type(4)));
typedef float  f32x16 __attribute__((ext_vector_type(16)));

// SESSION RULES (hard-won):
//  - no cross-kernel dataflow through d_ws (R5/R6); d_out is proven.
//  - NUMERICS: full 3-term split mandatory (R12: 2-term -> cphase 361 deg).
//  - CLOSED LEVERS: R18 dbuf; R2 co-resident blocks; R4 1-wave/SIMD ILP;
//    R5 cross-barrier reg pipelining (spills; ZERO headroom at 2 w/SIMD);
//    R6 KC=64 (regressed, mech unknown); R7 x-first staging (regressed:
//    coalescing is PER-LANE contiguity, not per-thread).
//  - THIS ROUND: MFMA 16x16x32 -> 32x32x16, operands swapped (A=img from
//    LDS rows=x k=y; B=Ev in-register, col=m=lane&31). Mechanism: better
//    rate (2382 vs 2075 TF), half the MFMA instrs, HALF the ds_reads
//    (16 vs 32 b128/wave/chunk). C: col=lane&31(m), row=(reg&3)+8*(reg>>2)
//    +4*(lane>>5)(x) [HW-verified m74/m101]. m-on-lanes => epilogue 3
//    sincosf/lane (was 8) + shfl_xor(32) + 2KB LDS x-half combine.
//    Staging (loads/convert/ds_write cadence) identical to R3. acc = 128
//    AGPR. KC=32, 2 barriers/chunk, (512,2).
//  - WRITE_SIZE is the spill tripwire (768 KB = clean).
//  - residual ~57 us outside the vis kernel is harness-fixed; vis is the
//    only lever.
// LDS window (x,y-octet): 16B lane stride within 32-lane groups -> 2-way
// bank aliasing only (free, m136). Wave A-read: 64 lanes cover 1024B
// contiguous (halves at +512B) -> free.
#define WIDX32(x, o) (((x) >> 5) * 1024 + (o) * 256 + ((x) & 31) * 8)

// range reduction: theta == k*n (mod 2pi) in [-pi,pi] (keeps sincosf fast).
__device__ __forceinline__ float red2pi(float k, float n)
{
    const double t = (double)k * (double)n * 0.15915494309189535;  // /(2pi)
    const double f = t - rint(t);
    return (float)(f * 6.283185307179586);
}

// Block: 128 m x 256 x x 1 batch, 8 waves. Wave w: m-rows [32*(w>>1),+32),
// x-half (w&1)*128. Stage 1 (MFMA): D[x,m] = sum_y img[y,x]*Ev[m,y],
// 3-term split (hh, lh, hl) per plane. Stage 2 in-register per lane (m).
__global__ __launch_bounds__(NT, 2)
void nufft_vis_mfma(const float* __restrict__ images,
                    const float* __restrict__ ktraj,
                    const float* __restrict__ pulsefac,
                    float* __restrict__ out)
{
    __shared__ __align__(16) __bf16 sBh[NPIX * KC];   // 16 KB img hi
    __shared__ __align__(16) __bf16 sBl[NPIX * KC];   // 16 KB img lo

    const int tid  = threadIdx.x;
    const int m0   = blockIdx.x * TMB;
    const int b    = blockIdx.y;
    const int lane = tid & 63;
    const int w    = tid >> 6;        // wave 0..7
    const int wm   = w >> 1;          // m-group 0..3
    const int wx   = w & 1;           // x-half 0..1
    const int l31  = lane & 31;
    const int hi   = lane >> 5;       // k-octet half 0..1

    // ---- B (Ev) rotor state: lane owns col m = m0 + wm*32 + l31,
    // k-octet = hi. Ev = exp(-i*kv*(y-128)); kv = ktraj[0][m].
    const int mlane = m0 + wm * 32 + l31;
    const float kvm = ktraj[mlane];
    float r1s, r1c, r16s, r16c, as_, ac_;
    sincosf(kvm, &r1s, &r1c);                          // rot1
    sincosf(red2pi(kvm, 16.0f), &r16s, &r16c);         // rot16 (per K-step)
    sincosf(red2pi(kvm, (float)(hi * 8 - 128)), &as_, &ac_);  // anchor @ y0=0
    float anr = ac_, ani = -as_;

    // A (img) staging: x = tid&255, y-octet pair = (tid>>8)*2 .. +1
    const int bx    = tid & 255;
    const int bhalf = tid >> 8;       // 0..1
    const float* imgb = images + b * NPIX * NPIX + bx;

    // gen Ev fragments for current K-step (8 y's), advance anchor by 16
    auto genB = [&](bf16x8& Rh, bf16x8& Rl, bf16x8& Ih, bf16x8& Il) {
        float er = anr, ei = ani;
        #pragma unroll
        for (int j = 0; j < 8; ++j) {
            __bf16 h = (__bf16)er;
            Rh[j] = h; Rl[j] = (__bf16)(er - (float)h);
            h = (__bf16)ei;
            Ih[j] = h; Il[j] = (__bf16)(ei - (float)h);
            const float nr = er * r1c + ei * r1s;   // *= e^{-i*kvm}
            const float ni = ei * r1c - er * r1s;
            er = nr; ei = ni;
        }
        const float nr = anr * r16c + ani * r16s;   // anchor *= e^{-i*kv*16}
        const float ni = ani * r16c - anr * r16s;
        anr = nr; ani = ni;
    };

    f32x16 acc[2][4];                 // [plane re/im][x-tile]
    #pragma unroll
    for (int p = 0; p < 2; ++p)
        #pragma unroll
        for (int xt = 0; xt < 4; ++xt)
            #pragma unroll
            for (int rg = 0; rg < 16; ++rg)
                acc[p][xt][rg] = 0.f;

    for (int c = 0; c < NPIX / KC; ++c) {
        const int y0 = c * KC;

        // ---- Ev fragments for K-step 0 (y = y0 + hi*8 ..)
        bf16x8 eRh, eRl, eIh, eIl;
        genB(eRh, eRl, eIh, eIl);

        // ---- stage img: lane-consecutive x, strided y (proven R3 pattern)
        #pragma unroll
        for (int oo = 0; oo < 2; ++oo) {
            const int oct = bhalf * 2 + oo;
            bf16x8 bh, bl;
            #pragma unroll
            for (int j = 0; j < 8; ++j) {
                const float v = imgb[(y0 + oct * 8 + j) * NPIX];
                const __bf16 h = (__bf16)v;
                bh[j] = h; bl[j] = (__bf16)(v - (float)h);
            }
            const int bo = WIDX32(bx, oct);
            *(bf16x8*)&sBh[bo] = bh;
            *(bf16x8*)&sBl[bo] = bl;
        }
        __syncthreads();

        // ---- MFMA K-step 0: A-octet = hi, B = frags above
        #pragma unroll
        for (int xt = 0; xt < 4; ++xt) {
            const int aro = (wx * 4 + xt) * 1024 + hi * 256 + l31 * 8;
            const bf16x8 ah = *(const bf16x8*)&sBh[aro];
            const bf16x8 al = *(const bf16x8*)&sBl[aro];
            acc[0][xt] = __builtin_amdgcn_mfma_f32_32x32x16_bf16(ah, eRh, acc[0][xt], 0, 0, 0);
            acc[0][xt] = __builtin_amdgcn_mfma_f32_32x32x16_bf16(al, eRh, acc[0][xt], 0, 0, 0);
            acc[0][xt] = __builtin_amdgcn_mfma_f32_32x32x16_bf16(ah, eRl, acc[0][xt], 0, 0, 0);
            acc[1][xt] = __builtin_amdgcn_mfma_f32_32x32x16_bf16(ah, eIh, acc[1][xt], 0, 0, 0);
            acc[1][xt] = __builtin_amdgcn_mfma_f32_32x32x16_bf16(al, eIh, acc[1][xt], 0, 0, 0);
            acc[1][xt] = __builtin_amdgcn_mfma_f32_32x32x16_bf16(ah, eIl, acc[1][xt], 0, 0, 0);
        }

        // ---- Ev fragments for K-step 1 (y = y0 + 16 + hi*8 ..)
        genB(eRh, eRl, eIh, eIl);

        // ---- MFMA K-step 1: A-octet = 2 + hi
        #pragma unroll
        for (int xt = 0; xt < 4; ++xt) {
            const int aro = (wx * 4 + xt) * 1024 + (2 + hi) * 256 + l31 * 8;
            const bf16x8 ah = *(const bf16x8*)&sBh[aro];
            const bf16x8 al = *(const bf16x8*)&sBl[aro];
            acc[0][xt] = __builtin_amdgcn_mfma_f32_32x32x16_bf16(ah, eRh, acc[0][xt], 0, 0, 0);
            acc[0][xt] = __builtin_amdgcn_mfma_f32_32x32x16_bf16(al, eRh, acc[0][xt], 0, 0, 0);
            acc[0][xt] = __builtin_amdgcn_mfma_f32_32x32x16_bf16(ah, eRl, acc[0][xt], 0, 0, 0);
            acc[1][xt] = __builtin_amdgcn_mfma_f32_32x32x16_bf16(ah, eIh, acc[1][xt], 0, 0, 0);
            acc[1][xt] = __builtin_amdgcn_mfma_f32_32x32x16_bf16(al, eIh, acc[1][xt], 0, 0, 0);
            acc[1][xt] = __builtin_amdgcn_mfma_f32_32x32x16_bf16(ah, eIl, acc[1][xt], 0, 0, 0);
        }
        __syncthreads();
    }

    // ---- fused stage 2: lane owns m = mlane; sum over its 64 x's.
    // C row = x_local = xt*32 + (rg&3) + 8*(rg>>2) + 4*hi; step +1,+1,+1,+5.
    {
        const float kum = ktraj[MM + mlane];
        float s1u, c1u, s5u, c5u, s0u, c0u;
        sincosf(kum, &s1u, &c1u);                      // rot1
        sincosf(red2pi(kum, 5.0f), &s5u, &c5u);        // rot5
        sincosf(red2pi(kum, (float)(wx * 128 + 4 * hi - 128)), &s0u, &c0u);
        float er = c0u, ei = -s0u;    // Eu at first x of this lane
        float sr = 0.f, si = 0.f;
        #pragma unroll
        for (int xt = 0; xt < 4; ++xt) {
            #pragma unroll
            for (int rg = 0; rg < 16; ++rg) {
                const float tr = acc[0][xt][rg];
                const float ti = acc[1][xt][rg];
                sr = fmaf(tr, er, fmaf(-ti, ei, sr));
                si = fmaf(tr, ei, fmaf(ti, er, si));
                const float cs = ((rg & 3) == 3) ? c5u : c1u;
                const float sn = ((rg & 3) == 3) ? s5u : s1u;
                const float nr = er * cs + ei * sn;     // advance rotor
                const float ni = ei * cs - er * sn;
                er = nr; ei = ni;
            }
        }
        // combine the two k-octet halves (same m, disjoint x sets)
        sr += __shfl_xor(sr, 32);
        si += __shfl_xor(si, 32);

        // cross-wave x-half combine via LDS (sBh reused; last barrier done)
        float2* sPart = (float2*)sBh;     // [128 m][2 wx]
        if (l31 == lane) {                // lane < 32
            sPart[(wm * 32 + l31) * 2 + wx] = make_float2(sr, si);
        }
    }
    __syncthreads();
    if (tid < TMB) {
        const float2* sPart = (const float2*)sBh;
        const float2 p0 = sPart[tid * 2 + 0];
        const float2 p1 = sPart[tid * 2 + 1];
        const float sr = p0.x + p1.x;
        const float si = p0.y + p1.y;
        const int m = m0 + tid;
        const float pr = pulsefac[m];
        const float pi = pulsefac[MM + m];
        const float vr = sr * pr - si * pi;
        const float vi = sr * pi + si * pr;
        out[b * 2 * MM + m]      = vr;
        out[b * 2 * MM + MM + m] = vi;
        out[VISAMP_OFF + b * MM + m] = sqrtf(vr * vr + vi * vi + EPSF);
    }
}

// polynomial atan2 (A&S 4.4.49, err <= ~1e-5 rad), fully predicated
__device__ __forceinline__ float fast_atan2f(float y, float x)
{
    const float ax = fabsf(x), ay = fabsf(y);
    const float mx = fmaxf(ax, ay), mn = fminf(ax, ay);
    const float a  = mn / fmaxf(mx, 1e-37f);
    const float s  = a * a;
    float r = 0.0208351f;
    r = fmaf(r, s, -0.0851330f);
    r = fmaf(r, s,  0.1801410f);
    r = fmaf(r, s, -0.3302995f);
    r = fmaf(r, s,  0.9998660f);
    r *= a;
    r = (ay > ax) ? (1.57079632679f - r) : r;
    r = (x < 0.0f) ? (3.14159265359f - r) : r;
    return (y < 0.0f) ? -r : r;
}

// fused cphase + logcamp. Each block serves ONE batch (NCP % 256 == 0):
// stage that batch's vis (64 KB) into LDS, scatters hit LDS.
__global__ __launch_bounds__(256)
void gather_fused(const float* __restrict__ vis,
                  const float* __restrict__ sign,
                  const int* __restrict__ cind,
                  const int* __restrict__ caind,
                  float* __restrict__ out)
{
    __shared__ float sv[2 * MM];      // 64 KB: [0,MM)=re, [MM,2MM)=im

    const int i = blockIdx.x * 256 + threadIdx.x;
    const int b = i / NCP;
    const int n = i - b * NCP;

    {
        const float4* g4 = (const float4*)(vis + b * 2 * MM);
        float4* s4 = (float4*)sv;
        #pragma unroll
        for (int j = 0; j < (2 * MM / 4) / 256; ++j)
            s4[j * 256 + threadIdx.x] = g4[j * 256 + threadIdx.x];
    }
    __syncthreads();

    float cp = 0.f;
    #pragma unroll
    for (int k = 0; k < 3; ++k) {
        const int m = cind[k * NCP + n];
        cp += sign[k * NCP + n] * fast_atan2f(sv[MM + m], sv[m]);
    }
    out[CPH_OFF + i] = cp * 57.29577951308232f;   // 180/pi

    // logcamp = 0.5*log((p1*p2)/(p3*p4)), p = vr^2+vi^2+eps — one log call
    float p[4];
    #pragma unroll
    for (int k = 0; k < 4; ++k) {
        const int m = caind[k * NCA + n];
        const float vr = sv[m];
        const float vi = sv[MM + m];
        p[k] = vr * vr + vi * vi + EPSF;
    }
    out[LCA_OFF + i] = 0.5f * __logf((p[0] * p[1]) / (p[2] * p[3]));
}

extern "C" void kernel_launch(void* const* d_in, const int* in_sizes, int n_in,
                              void* d_out, int out_size, void* d_ws, size_t ws_size,
                              hipStream_t stream)
{
    const float* images   = (const float*)d_in[0];
    const float* ktraj    = (const float*)d_in[1];
    const float* pulsefac = (const float*)d_in[2];
    const float* csign    = (const float*)d_in[3];
    const int*   cind     = (const int*)d_in[4];
    const int*   caind    = (const int*)d_in[5];
    float* out = (float*)d_out;

    dim3 grid(MM / TMB, BB);
    nufft_vis_mfma<<<grid, NT, 0, stream>>>(images, ktraj, pulsefac, out);
    gather_fused<<<BB * NCP / 256, 256, 0, stream>>>(out, csign, cind, caind, out);
}